// Round 1
// baseline (2907.178 us; speedup 1.0000x reference)
//
#include <hip/hip_runtime.h>

// ---------------------------------------------------------------------------
// self_LSTM_sparse_attn — MI355X persistent-kernel, round 11.
//
// R10 theory: ~192 broadcast ds_read_b128 per thread per step (weight rows
// Wh[k][0..7]/Wx[k][0..7], same address in all 64 lanes) consumed the LDS
// pipe (~1536 wave-level LDS instrs/CU/step) and serialized every FMA behind
// lgkmcnt. Weights are wave-uniform -> moved to the SCALAR pipe: inline-asm
// s_load_dwordx16 batches read each row's contiguous k-slice directly from
// W_hh/W_ih into SGPRs; FMAs become v_fmac_f32 vacc, s_w, v_h (1 sgpr read
// per VALU instr, legal). Explicit asm (not compiler SMEM formation) because
// the st_lic/ld_lic "memory" clobbers in the loop block the uniform-load
// annotation. s_waitcnt lgkmcnt(0) sits INSIDE each load block so the
// register dependence on asm outputs orders the consuming FMAs (rule #18).
// LDS weight staging deleted (43KB -> ~18KB LDS). Math stays fp32; per-wave
// summation order changes identically on all 8 waves, so the replicated-tail
// bit-identity invariant holds.
//
// Carried invariants (R5-R8-verified): cross-WG data write-once per step;
// cross-WG stores direct to LIC via sc0 sc1 (no fences anywhere); flag[g]
// stored only after the __syncthreads vmcnt-drain of g's plane stores;
// per-wave producer wait (wave kqu's psum slots AND mem dims both produced
// by WGs [32kqu,32kqu+32), lane polls flag[32kqu+(b&31)]).
// Algorithm (R2-R8-verified): s_h cancels in attention weights; w <=4-sparse;
// WG g owns h dims {2g,2g+1}; mem[i] == h_out(i-1); incremental top-5 with
// register-carried gather values (qa,qb).
// ---------------------------------------------------------------------------

#define T_N 256
#define B_N 64
#define I_N 256
#define H_N 512
#define C_N 64
#define EPSF 1e-7f

typedef float v4f __attribute__((ext_vector_type(4)));
typedef float v2f __attribute__((ext_vector_type(2)));
typedef float f16s __attribute__((ext_vector_type(16)));

// ws layout (float offsets). Packed layouts: [..][k4][b][u] u=k&3.
#define XT4_F   0u          // [T][64][64][4]    x packed          (4,194,304)
#define MEM4_F  4194304u    // [T+1][128][64][4] h_out history     (8,421,376)
#define MSEQ4_F 12615680u   // [T][128][64][4]   m_seq             (8,388,608)
#define PSUM4_F 21004288u   // [T+1][64][64][4]  score partials, write-once (4,210,688)
#define FCWT_F  25214976u   // [2H][C] fc_w transposed             (65,536)
#define FLAG_F  25280512u   // [256] arrival flags, packed u32     (256)
#define TOT_F   25280768u

__device__ __forceinline__ float sigf(float x) { return 1.0f / (1.0f + expf(-x)); }

// direct-to-LIC (coherence point) ops — no fences needed anywhere.
__device__ __forceinline__ void st_lic_f32(float* p, float v) {
  asm volatile("global_store_dword %0, %1, off sc0 sc1" :: "v"(p), "v"(v) : "memory");
}
__device__ __forceinline__ void st_lic_f32x2(float* p, v2f v) {
  asm volatile("global_store_dwordx2 %0, %1, off sc0 sc1" :: "v"(p), "v"(v) : "memory");
}
__device__ __forceinline__ void st_lic_u32(unsigned* p, unsigned v) {
  asm volatile("global_store_dword %0, %1, off sc0 sc1" :: "v"(p), "v"(v) : "memory");
}
__device__ __forceinline__ unsigned ld_lic_u32(const unsigned* p) {
  unsigned r;
  asm volatile("global_load_dword %0, %1, off sc0 sc1\n\ts_waitcnt vmcnt(0)"
               : "=v"(r) : "v"(p) : "memory");
  return r;
}

// scalar-pipe weight row loads. Wait INSIDE the block: consumers depend on
// the asm outputs, so they cannot be hoisted above the lgkmcnt drain.
__device__ __forceinline__ void sload_row64(const float* p, f16s& a, f16s& b,
                                            f16s& c, f16s& d) {
  asm volatile("s_load_dwordx16 %0, %4, 0x0\n\t"
               "s_load_dwordx16 %1, %4, 0x40\n\t"
               "s_load_dwordx16 %2, %4, 0x80\n\t"
               "s_load_dwordx16 %3, %4, 0xc0\n\t"
               "s_waitcnt lgkmcnt(0)"
               : "=s"(a), "=s"(b), "=s"(c), "=s"(d)
               : "s"(p));
}
__device__ __forceinline__ void sload_row32(const float* p, f16s& a, f16s& b) {
  asm volatile("s_load_dwordx16 %0, %2, 0x0\n\t"
               "s_load_dwordx16 %1, %2, 0x40\n\t"
               "s_waitcnt lgkmcnt(0)"
               : "=s"(a), "=s"(b)
               : "s"(p));
}

// insert (s, a0, a1) into descending top-5; slots 0..3 carry values (qa,qb)
__device__ __forceinline__ void ins5v(float s, float a0, float a1,
    float& v0, float& v1, float& v2, float& v3, float& v4,
    float& qa0, float& qb0, float& qa1, float& qb1,
    float& qa2, float& qb2, float& qa3, float& qb3) {
  if (s > v4) {
    if (s > v0) {
      v4=v3; v3=v2; qa3=qa2; qb3=qb2; v2=v1; qa2=qa1; qb2=qb1;
      v1=v0; qa1=qa0; qb1=qb0; v0=s; qa0=a0; qb0=a1;
    } else if (s > v1) {
      v4=v3; v3=v2; qa3=qa2; qb3=qb2; v2=v1; qa2=qa1; qb2=qb1;
      v1=s; qa1=a0; qb1=a1;
    } else if (s > v2) {
      v4=v3; v3=v2; qa3=qa2; qb3=qb2; v2=s; qa2=a0; qb2=a1;
    } else if (s > v3) {
      v4=v3; v3=s; qa3=a0; qb3=a1;
    } else {
      v4=s;
    }
  }
}

__global__ void poison_k(float* out, int n) {
  int i = blockIdx.x * 256 + threadIdx.x;
  if (i < n) out[i] = __int_as_float(0x7fc00000);
}

// blocks 0..1023: x -> xT4 packed; blocks 1024..1039: fc_w -> fcwT[d][c]
__global__ void init_k(const float* __restrict__ x, const float* __restrict__ fc_w,
                       float* __restrict__ ws) {
  __shared__ float tile[64][65];
  const int blk = blockIdx.x, tid = threadIdx.x;
  if (blk < 1024) {
    const int t = blk >> 2, k0 = (blk & 3) * 64;
    for (int u = tid; u < 4096; u += 256) {
      int bb = u >> 6, kk = u & 63;
      tile[kk][bb] = x[((unsigned)t * 64u + bb) * 256u + k0 + kk];
    }
    __syncthreads();
    for (int u = tid; u < 4096; u += 256) {
      int kk = u >> 6, bb = u & 63;
      int k = k0 + kk;
      ws[XT4_F + (unsigned)t * 16384u + (unsigned)(k >> 2) * 256u
         + (unsigned)bb * 4u + (unsigned)(k & 3)] = tile[kk][bb];
    }
  } else {
    const int d0 = (blk - 1024) * 64;
    for (int u = tid; u < 4096; u += 256) {
      int cc = u >> 6, dd = u & 63;
      tile[dd][cc] = fc_w[(unsigned)cc * 1024u + d0 + dd];
    }
    __syncthreads();
    for (int u = tid; u < 4096; u += 256) {
      int dd = u >> 6, cc = u & 63;
      ws[FCWT_F + (unsigned)(d0 + dd) * 64u + cc] = tile[dd][cc];
    }
  }
}

__launch_bounds__(512, 1)
__global__ void lstm_main(const float* __restrict__ W_ih, const float* __restrict__ W_hh,
                          const float* __restrict__ b_ih, const float* __restrict__ b_hh,
                          const float* __restrict__ w_t, float* __restrict__ ws) {
  __shared__ float red2[8][4][B_N][2];   // 16 KB gate partials (row pairs)
  __shared__ float psum[8][B_N];         // 2 KB

  const int g = blockIdx.x;
  const int tid = threadIdx.x;
  const int b = tid & 63;
  const int kqu = __builtin_amdgcn_readfirstlane(tid >> 6);  // wave id 0..7

  unsigned int* flags = (unsigned int*)(ws + FLAG_F);

  float bias_r[8];
  #pragma unroll
  for (int r = 0; r < 8; ++r) {
    int grow = (r >> 1) * H_N + 2 * g + (r & 1);
    bias_r[r] = b_ih[grow] + b_hh[grow];
  }
  const float wt20 = w_t[H_N + 2 * g];
  const float wt21 = w_t[H_N + 2 * g + 1];

  // per-wave replicated state (bit-identical streams across waves)
  float cs0 = 0.0f, cs1 = 0.0f;                 // LSTM c-state
  float po0 = 0.0f, po1 = 0.0f;                 // ho(i-1) == mem[i] values (own dims)
  float v0 = -3e38f, v1 = -3e38f, v2 = -3e38f, v3 = -3e38f, v4 = -3e38f;
  float qa0 = 0, qb0 = 0, qa1 = 0, qb1 = 0, qa2 = 0, qb2 = 0, qa3 = 0, qb3 = 0;
  float mn = 3e38f;

  const unsigned hoff0 = (unsigned)(g >> 1) * 256u + (unsigned)b * 4u + (unsigned)((g & 1) * 2);

  // prologue: x-part of step 0's matvec (k-eighth per wave, scalar weights)
  float xacc[8];
  {
    const v4f* xp = (const v4f*)(ws + XT4_F) + (unsigned)(kqu * 8) * 64u + b;
    v4f xv[8];
    #pragma unroll
    for (int j = 0; j < 8; ++j) xv[j] = xp[j * 64];
    #pragma unroll
    for (int r = 0; r < 8; ++r) {
      const float* xr = W_ih
          + (unsigned)((r >> 1) * H_N + 2 * g + (r & 1)) * (unsigned)I_N
          + (unsigned)(kqu * 32);
      f16s xa, xb;
      sload_row32(xr, xa, xb);
      float a0 = 0.0f, a1 = 0.0f, a2 = 0.0f, a3 = 0.0f;
      #pragma unroll
      for (int j = 0; j < 4; ++j) {
        a0 += xa[4 * j + 0] * xv[j][0];
        a1 += xa[4 * j + 1] * xv[j][1];
        a2 += xa[4 * j + 2] * xv[j][2];
        a3 += xa[4 * j + 3] * xv[j][3];
      }
      #pragma unroll
      for (int j = 0; j < 4; ++j) {
        a0 += xb[4 * j + 0] * xv[4 + j][0];
        a1 += xb[4 * j + 1] * xv[4 + j][1];
        a2 += xb[4 * j + 2] * xv[4 + j][2];
        a3 += xb[4 * j + 3] * xv[4 + j][3];
      }
      xacc[r] = (a0 + a1) + (a2 + a3);
    }
  }

  for (int i = 0; i < T_N; ++i) {
    // ---- S0: per-wave producer wait. Wave kqu's psum slots AND mem dims
    // are both written exactly by WGs [32kqu, 32kqu+32). ----
    if (i > 0) {
      const unsigned* fp = flags + (kqu * 32 + (b & 31));
      while (ld_lic_u32(fp) < (unsigned)i) __builtin_amdgcn_s_sleep(1);
    }

    // ---- Phase A: batched vector loads; weights on the scalar pipe ----
    v4f pv[8];
    {
      const v4f* pp = (const v4f*)(ws + PSUM4_F) + (unsigned)i * 4096u
                      + (unsigned)(kqu * 8) * 64u + b;
      #pragma unroll
      for (int j = 0; j < 8; ++j) pv[j] = pp[j * 64];
    }
    v4f hv[16];
    {
      const v4f* hp = (const v4f*)(ws + MEM4_F) + (unsigned)i * 8192u
                      + (unsigned)(kqu * 16) * 64u + b;  // mem[i] == h_out(i-1)
      #pragma unroll
      for (int j = 0; j < 16; ++j) hv[j] = hp[j * 64];
    }
    float ps = 0.0f;
    #pragma unroll
    for (int j = 0; j < 8; ++j) ps += (pv[j][0] + pv[j][1]) + (pv[j][2] + pv[j][3]);
    psum[kqu][b] = ps;

    float acc[8];
    #pragma unroll
    for (int r = 0; r < 8; ++r) {
      const float* wr = W_hh
          + (unsigned)((r >> 1) * H_N + 2 * g + (r & 1)) * (unsigned)H_N
          + (unsigned)(kqu * 64);
      f16s wa, wb, wc, wd;
      sload_row64(wr, wa, wb, wc, wd);
      float a0 = 0.0f, a1 = 0.0f, a2 = 0.0f, a3 = 0.0f;
      #pragma unroll
      for (int j = 0; j < 4; ++j) {
        a0 += wa[4 * j + 0] * hv[j][0];
        a1 += wa[4 * j + 1] * hv[j][1];
        a2 += wa[4 * j + 2] * hv[j][2];
        a3 += wa[4 * j + 3] * hv[j][3];
      }
      #pragma unroll
      for (int j = 0; j < 4; ++j) {
        a0 += wb[4 * j + 0] * hv[4 + j][0];
        a1 += wb[4 * j + 1] * hv[4 + j][1];
        a2 += wb[4 * j + 2] * hv[4 + j][2];
        a3 += wb[4 * j + 3] * hv[4 + j][3];
      }
      #pragma unroll
      for (int j = 0; j < 4; ++j) {
        a0 += wc[4 * j + 0] * hv[8 + j][0];
        a1 += wc[4 * j + 1] * hv[8 + j][1];
        a2 += wc[4 * j + 2] * hv[8 + j][2];
        a3 += wc[4 * j + 3] * hv[8 + j][3];
      }
      #pragma unroll
      for (int j = 0; j < 4; ++j) {
        a0 += wd[4 * j + 0] * hv[12 + j][0];
        a1 += wd[4 * j + 1] * hv[12 + j][1];
        a2 += wd[4 * j + 2] * hv[12 + j][2];
        a3 += wd[4 * j + 3] * hv[12 + j][3];
      }
      acc[r] = xacc[r] + ((a0 + a1) + (a2 + a3));
    }
    #pragma unroll
    for (int p = 0; p < 4; ++p) {
      red2[kqu][p][b][0] = acc[2 * p];
      red2[kqu][p][b][1] = acc[2 * p + 1];
    }
    __syncthreads();  // S1

    // ---- replicated tail (all 8 waves, bit-identical; no memory gather) ----
    float sc = ((psum[0][b] + psum[1][b]) + (psum[2][b] + psum[3][b]))
             + ((psum[4][b] + psum[5][b]) + (psum[6][b] + psum[7][b]));
    ins5v(sc, po0, po1, v0, v1, v2, v3, v4,
          qa0, qb0, qa1, qb1, qa2, qb2, qa3, qb3);
    mn = fminf(mn, sc);
    float delta = ((i + 1) <= 5 ? mn : v4) + EPSF;
    float w0 = fmaxf(v0 - delta, 0.0f);
    float w1 = fmaxf(v1 - delta, 0.0f);
    float w2 = fmaxf(v2 - delta, 0.0f);
    float w3 = fmaxf(v3 - delta, 0.0f);
    float inv = 1.0f / (w0 + w1 + w2 + w3 + EPSF);
    w0 *= inv; w1 *= inv; w2 *= inv; w3 *= inv;

    float G[8];
    #pragma unroll
    for (int r = 0; r < 8; ++r) G[r] = bias_r[r];
    #pragma unroll
    for (int q = 0; q < 8; ++q) {
      #pragma unroll
      for (int p = 0; p < 4; ++p) {
        G[2 * p]     += red2[q][p][b][0];
        G[2 * p + 1] += red2[q][p][b][1];
      }
    }

    float cn0 = sigf(G[2]) * cs0 + sigf(G[0]) * tanhf(G[4]);
    float hn0 = sigf(G[6]) * tanhf(cn0);
    float cn1 = sigf(G[3]) * cs1 + sigf(G[1]) * tanhf(G[5]);
    float hn1 = sigf(G[7]) * tanhf(cn1);
    cs0 = cn0; cs1 = cn1;

    float m0 = w0 * qa0 + w1 * qa1 + w2 * qa2 + w3 * qa3;  // registers, no gather
    float m1 = w0 * qb0 + w1 * qb1 + w2 * qb2 + w3 * qb3;
    float ho0 = hn0 + m0, ho1 = hn1 + m1;
    po0 = ho0; po1 = ho1;  // becomes mem[i+1] value for future insertions

    // disjoint store shares per wave
    if (kqu == 0) {
      v2f hov; hov[0] = ho0; hov[1] = ho1;
      st_lic_f32x2(ws + MEM4_F + (unsigned)(i + 1) * 32768u + hoff0, hov);
    } else if (kqu == 1) {
      v2f mv; mv[0] = m0; mv[1] = m1;
      *(v2f*)(ws + MSEQ4_F + (unsigned)i * 32768u + hoff0) = mv;  // out_gemm-only
    } else if (kqu == 2) {
      st_lic_f32(ws + PSUM4_F + (unsigned)(i + 1) * 16384u + (unsigned)(g >> 2) * 256u
                 + (unsigned)b * 4u + (unsigned)(g & 3),
                 tanhf(ho0) * wt20 + tanhf(ho1) * wt21);
    }
    __syncthreads();  // S2 — per-wave vmcnt(0) drain: all shares at LIC
    if (tid == 0) st_lic_u32(&flags[g], (unsigned)(i + 1));

    // ---- overlap: x-part of NEXT step's matvec (static xT4, scalar weights) ----
    if (i + 1 < T_N) {
      const v4f* xp = (const v4f*)(ws + XT4_F) + (unsigned)(i + 1) * 4096u
                      + (unsigned)(kqu * 8) * 64u + b;
      v4f xv[8];
      #pragma unroll
      for (int j = 0; j < 8; ++j) xv[j] = xp[j * 64];
      #pragma unroll
      for (int r = 0; r < 8; ++r) {
        const float* xr = W_ih
            + (unsigned)((r >> 1) * H_N + 2 * g + (r & 1)) * (unsigned)I_N
            + (unsigned)(kqu * 32);
        f16s xa, xb;
        sload_row32(xr, xa, xb);
        float a0 = 0.0f, a1 = 0.0f, a2 = 0.0f, a3 = 0.0f;
        #pragma unroll
        for (int j = 0; j < 4; ++j) {
          a0 += xa[4 * j + 0] * xv[j][0];
          a1 += xa[4 * j + 1] * xv[j][1];
          a2 += xa[4 * j + 2] * xv[j][2];
          a3 += xa[4 * j + 3] * xv[j][3];
        }
        #pragma unroll
        for (int j = 0; j < 4; ++j) {
          a0 += xb[4 * j + 0] * xv[4 + j][0];
          a1 += xb[4 * j + 1] * xv[4 + j][1];
          a2 += xb[4 * j + 2] * xv[4 + j][2];
          a3 += xb[4 * j + 3] * xv[4 + j][3];
        }
        xacc[r] = (a0 + a1) + (a2 + a3);
      }
    }
  }
}

// out[t,b,c] = sum_d feats[t,d,b]*fcwT[d,c] + fc_b[c];
// feats h-half == mem4[t+1], m-half == mseq4[t] (packed [k4][b][4]).
__launch_bounds__(256, 4)
__global__ void out_gemm(const float* __restrict__ ws, const float* __restrict__ fc_b,
                         float* __restrict__ out) {
  __shared__ float fw[64][16];
  const int t = blockIdx.x >> 2, cg = blockIdx.x & 3;
  const int tid = threadIdx.x, b = tid & 63, cs = (tid >> 6) * 4;
  float acc[4] = {0.0f, 0.0f, 0.0f, 0.0f};
  const v4f* hsrc = (const v4f*)(ws + MEM4_F) + (unsigned)(t + 1) * 8192u + b;
  const v4f* msrc = (const v4f*)(ws + MSEQ4_F) + (unsigned)t * 8192u + b;
  for (int half = 0; half < 2; ++half) {
    const v4f* src = half ? msrc : hsrc;
    for (int dt = 0; dt < 512; dt += 64) {
      __syncthreads();
      for (int u = tid; u < 1024; u += 256) {
        int dd = u >> 4, cc = u & 15;
        fw[dd][cc] = ws[FCWT_F + (unsigned)(half * 512 + dt + dd) * 64u + cg * 16 + cc];
      }
      __syncthreads();
      #pragma unroll 4
      for (int j = 0; j < 16; ++j) {
        v4f f4 = src[(unsigned)(dt / 4 + j) * 64u];
        #pragma unroll
        for (int u = 0; u < 4; ++u) {
          float f = f4[u];
          const float* wr = &fw[4 * j + u][cs];
          #pragma unroll
          for (int c4 = 0; c4 < 4; ++c4) acc[c4] += f * wr[c4];
        }
      }
    }
  }
  float* op = out + ((unsigned)t * 64u + b) * 64u + cg * 16 + cs;
  #pragma unroll
  for (int c4 = 0; c4 < 4; ++c4) op[c4] = acc[c4] + fc_b[cg * 16 + cs + c4];
}

extern "C" void kernel_launch(void* const* d_in, const int* in_sizes, int n_in,
                              void* d_out, int out_size, void* d_ws, size_t ws_size,
                              hipStream_t stream) {
  const float* x    = (const float*)d_in[0];
  const float* W_ih = (const float*)d_in[1];
  const float* W_hh = (const float*)d_in[2];
  const float* b_ih = (const float*)d_in[3];
  const float* b_hh = (const float*)d_in[4];
  const float* w_t  = (const float*)d_in[5];
  const float* fc_w = (const float*)d_in[6];
  const float* fc_b = (const float*)d_in[7];
  float* out = (float*)d_out;
  float* ws  = (float*)d_ws;

  if (ws_size < (size_t)TOT_F * 4u) {
    poison_k<<<(out_size + 255) / 256, 256, 0, stream>>>(out, out_size);
    return;
  }

  hipMemsetAsync(ws + MEM4_F, 0, (size_t)32768u * 4u, stream);     // mem[0] = 0
  hipMemsetAsync(ws + PSUM4_F, 0, (size_t)16384u * 4u, stream);    // psum plane 0
  hipMemsetAsync(ws + FLAG_F, 0, 256u * 4u, stream);               // flags

  init_k<<<1040, 256, 0, stream>>>(x, fc_w, ws);
  lstm_main<<<256, 512, 0, stream>>>(W_ih, W_hh, b_ih, b_hh, w_t, ws);
  out_gemm<<<1024, 256, 0, stream>>>(ws, fc_b, out);
}